// Round 6
// baseline (66.879 us; speedup 1.0000x reference)
//
#include <hip/hip_runtime.h>

// Chamfer loss via MFMA: X, Y f32 [8, 3, 4096] -> scalar mean of (d1+d2)/2.
//
// d'(q,t) = ||t||^2 - 2 q.t  computed by ONE mfma_f32_16x16x32_bf16 per
// 16x16 (q,t)-tile using hi/lo-split bf16 packing (error ~1e-4 << 7.3e-4):
//   A (query) k-slots: per coord c: [4c..4c+3] = (qh,qh,ql,ql), qh+ql ~= -2*q_c
//                      slots 12,13 = 1.0, 1.0
//   B (target) k-slots: per coord c: [4c..4c+3] = (th,tl,th,tl), th+tl ~= t_c
//                      slots 12,13 = rt_hi, rt_lo  (rt = ||t||^2)
//   dot = sum_c (qh+ql)(th+tl)*(-2 folded) + rt  = rt - 2 q.t
// min_t(||q-t||^2) = ||q||^2 + min_t d'; sum of ||q||^2 hoisted globally.
//
// prep:   pack Q-form + T-form (4 MB each) + per-block sum of ||p||^2.
// main:   1024 waves; wave = 4 strips of 16 q; loop 256 target tiles;
//         per tile: 4 MFMA + elementwise online-min (1 lane-op/distance).
// reduce: fixed-tree sum of 1024 wave partials + 256 ra partials.

typedef __attribute__((ext_vector_type(8))) short short8;
typedef __attribute__((ext_vector_type(4))) float f32x4;

constexpr int NPTS = 4096;
constexpr int NB   = 8;
constexpr int NPOINTS = 2 * NB * NPTS;            // 65536
constexpr size_t PACK_BYTES = (size_t)NPOINTS * 64;  // 4 MB per form

__device__ inline unsigned short f2bf(float x) {    // round-to-nearest-even
    unsigned u = __float_as_uint(x);
    unsigned r = u + 0x7fff + ((u >> 16) & 1);
    return (unsigned short)(r >> 16);
}
__device__ inline float bf2f(unsigned short h) {
    return __uint_as_float(((unsigned)h) << 16);
}

__global__ __launch_bounds__(256) void chamfer_prep(
    const float* __restrict__ X, const float* __restrict__ Y,
    unsigned short* __restrict__ Aq, unsigned short* __restrict__ Bt,
    float* __restrict__ raPart)
{
    const int P     = blockIdx.x * 256 + threadIdx.x;   // 0..65535
    const int cloud = P >> 15;                          // 0 = X, 1 = Y
    const int b     = (P >> 12) & 7;
    const int p     = P & 4095;

    const float* src = (cloud ? Y : X) + b * 3 * NPTS + p;
    const float v0 = src[0], v1 = src[NPTS], v2 = src[2 * NPTS];
    const float r  = fmaf(v0, v0, fmaf(v1, v1, v2 * v2));

    unsigned qw[16], tw[16];
    #pragma unroll
    for (int k = 7; k < 16; ++k) { qw[k] = 0; tw[k] = 0; }

    const float v[3] = {v0, v1, v2};
    #pragma unroll
    for (int c = 0; c < 3; ++c) {
        unsigned short th = f2bf(v[c]);
        unsigned short tl = f2bf(v[c] - bf2f(th));
        float m2 = -2.0f * v[c];
        unsigned short qh = f2bf(m2);
        unsigned short ql = f2bf(m2 - bf2f(qh));
        qw[2 * c]     = (unsigned)qh | ((unsigned)qh << 16);  // slots 4c,4c+1
        qw[2 * c + 1] = (unsigned)ql | ((unsigned)ql << 16);  // slots 4c+2,4c+3
        tw[2 * c]     = (unsigned)th | ((unsigned)tl << 16);
        tw[2 * c + 1] = (unsigned)th | ((unsigned)tl << 16);
    }
    qw[6] = 0x3F803F80u;                                   // slots 12,13 = 1.0,1.0
    unsigned short rh = f2bf(r);
    unsigned short rl = f2bf(r - bf2f(rh));
    tw[6] = (unsigned)rh | ((unsigned)rl << 16);           // slots 12,13 = rt hi/lo

    uint4* qa = (uint4*)(Aq + (size_t)P * 32);
    uint4* ta = (uint4*)(Bt + (size_t)P * 32);
    qa[0] = make_uint4(qw[0],  qw[1],  qw[2],  qw[3]);
    qa[1] = make_uint4(qw[4],  qw[5],  qw[6],  qw[7]);
    qa[2] = make_uint4(qw[8],  qw[9],  qw[10], qw[11]);
    qa[3] = make_uint4(qw[12], qw[13], qw[14], qw[15]);
    ta[0] = make_uint4(tw[0],  tw[1],  tw[2],  tw[3]);
    ta[1] = make_uint4(tw[4],  tw[5],  tw[6],  tw[7]);
    ta[2] = make_uint4(tw[8],  tw[9],  tw[10], tw[11]);
    ta[3] = make_uint4(tw[12], tw[13], tw[14], tw[15]);

    // Block sum of ||p||^2 (every point is a query in exactly one direction).
    __shared__ float wsum[4];
    float acc = r;
    #pragma unroll
    for (int off = 32; off > 0; off >>= 1) acc += __shfl_down(acc, off);
    if ((threadIdx.x & 63) == 0) wsum[threadIdx.x >> 6] = acc;
    __syncthreads();
    if (threadIdx.x == 0)
        raPart[blockIdx.x] = (wsum[0] + wsum[1]) + (wsum[2] + wsum[3]);
}

__global__ __launch_bounds__(256) void chamfer_mfma(
    const unsigned short* __restrict__ Aq, const unsigned short* __restrict__ Bt,
    float* __restrict__ wavePart)
{
    const int lane = threadIdx.x & 63;
    const int w    = blockIdx.x * 4 + (threadIdx.x >> 6);  // 0..1023
    const int pair = w >> 6;                               // 0..15
    const int dir  = pair >> 3;
    const int b    = pair & 7;
    const int strip0 = (w & 63) * 4;                       // 4 strips of 16 q

    // dir0: queries = X (cloud 0), targets = Y (cloud 1); dir1 swapped.
    const char* Abase = (const char*)(Aq + (size_t)((dir ? 1 : 0) * NB + b) * NPTS * 32);
    const char* Bbase = (const char*)(Bt + (size_t)((dir ? 0 : 1) * NB + b) * NPTS * 32);

    // Fragment lane mapping (A and B identical roles for 16x16x32):
    // outer index = lane&15, k = (lane>>4)*8 + j  -> 16 B at this byte offset.
    const int lsel = (lane & 15) * 64 + (lane >> 4) * 16;

    short8 A[4];
    #pragma unroll
    for (int s = 0; s < 4; ++s)
        A[s] = *(const short8*)(Abase + (size_t)(strip0 + s) * 1024 + lsel);

    f32x4 run[4];
    #pragma unroll
    for (int s = 0; s < 4; ++s)
        run[s] = (f32x4){3.4e38f, 3.4e38f, 3.4e38f, 3.4e38f};

    const f32x4 zero = (f32x4){0.f, 0.f, 0.f, 0.f};
    short8 f0 = *(const short8*)(Bbase + 0 * 1024 + lsel);
    short8 f1 = *(const short8*)(Bbase + 1 * 1024 + lsel);

    for (int t = 0; t < 256; t += 2) {
        const int t2 = (t + 2 < 256) ? t + 2 : 255;   // clamped dummy prefetch
        const int t3 = (t + 3 < 256) ? t + 3 : 255;
        #pragma unroll
        for (int s = 0; s < 4; ++s) {
            f32x4 d = __builtin_amdgcn_mfma_f32_16x16x32_bf16(A[s], f0, zero, 0, 0, 0);
            run[s][0] = fminf(run[s][0], d[0]);
            run[s][1] = fminf(run[s][1], d[1]);
            run[s][2] = fminf(run[s][2], d[2]);
            run[s][3] = fminf(run[s][3], d[3]);
        }
        f0 = *(const short8*)(Bbase + (size_t)t2 * 1024 + lsel);
        #pragma unroll
        for (int s = 0; s < 4; ++s) {
            f32x4 d = __builtin_amdgcn_mfma_f32_16x16x32_bf16(A[s], f1, zero, 0, 0, 0);
            run[s][0] = fminf(run[s][0], d[0]);
            run[s][1] = fminf(run[s][1], d[1]);
            run[s][2] = fminf(run[s][2], d[2]);
            run[s][3] = fminf(run[s][3], d[3]);
        }
        f1 = *(const short8*)(Bbase + (size_t)t3 * 1024 + lsel);
    }

    // D layout (m89-verified): col = lane&15 (t), row = (lane>>4)*4 + reg (q).
    // Min across the 16 col-lanes (butterfly over lane bits 0..3).
    #pragma unroll
    for (int st = 1; st < 16; st <<= 1) {
        #pragma unroll
        for (int s = 0; s < 4; ++s) {
            #pragma unroll
            for (int i = 0; i < 4; ++i)
                run[s][i] = fminf(run[s][i], __shfl_xor(run[s][i], st));
        }
    }
    // Per-lane partial: sum of its group's 16 q-mins; then sum the 4 groups.
    float psum = 0.0f;
    #pragma unroll
    for (int s = 0; s < 4; ++s)
        psum += (run[s][0] + run[s][1]) + (run[s][2] + run[s][3]);
    psum += __shfl_xor(psum, 16);
    psum += __shfl_xor(psum, 32);
    if (lane == 0) wavePart[w] = psum;
}

__global__ __launch_bounds__(256) void chamfer_final(
    const float* __restrict__ wavePart, const float* __restrict__ raPart,
    float* __restrict__ out)
{
    __shared__ float wsum[4];
    const int tid = threadIdx.x;
    float acc = raPart[tid];
    #pragma unroll
    for (int j = 0; j < 4; ++j) acc += wavePart[tid + j * 256];
    #pragma unroll
    for (int off = 32; off > 0; off >>= 1) acc += __shfl_down(acc, off);
    if ((tid & 63) == 0) wsum[tid >> 6] = acc;
    __syncthreads();
    if (tid == 0) {
        // mean over [B, N] of (d1+d2)/2 -> total / (2*8*4096)
        out[0] = ((wsum[0] + wsum[1]) + (wsum[2] + wsum[3])) * (1.0f / 65536.0f);
    }
}

extern "C" void kernel_launch(void* const* d_in, const int* in_sizes, int n_in,
                              void* d_out, int out_size, void* d_ws, size_t ws_size,
                              hipStream_t stream) {
    const float* X = (const float*)d_in[0];
    const float* Y = (const float*)d_in[1];

    unsigned short* Aq      = (unsigned short*)d_ws;                       // 4 MB
    unsigned short* Bt      = (unsigned short*)((char*)d_ws + PACK_BYTES); // 4 MB
    float*          wavePart = (float*)((char*)d_ws + 2 * PACK_BYTES);     // 1024 f32
    float*          raPart   = wavePart + 1024;                            // 256 f32
    float*          out      = (float*)d_out;

    chamfer_prep<<<256, 256, 0, stream>>>(X, Y, Aq, Bt, raPart);
    chamfer_mfma<<<256, 256, 0, stream>>>(Aq, Bt, wavePart);
    chamfer_final<<<1, 256, 0, stream>>>(wavePart, raPart, out);
}

// Round 7
// 36.683 us; speedup vs baseline: 1.8232x; 1.8232x over previous
//
#include <hip/hip_runtime.h>

// Chamfer loss via MFMA: X, Y f32 [8, 3, 4096] -> scalar mean of (d1+d2)/2.
//
// d'(q,t) = ||t||^2 - 2 q.t  by one mfma_f32_16x16x32_bf16 per 16x16 tile,
// hi/lo-split bf16 packing (verified R6, absmax 0):
//   A k-slots: per coord c: (qh,qh,ql,ql) with qh+ql ~= -2*q_c; slots 12,13 = 1
//   B k-slots: per coord c: (th,tl,th,tl) with th+tl ~= t_c; slots 12,13 = rt hi/lo
// min_t ||q-t||^2 = ||q||^2 + min_t d'; sum of ||q||^2 hoisted (raPart).
//
// prep: pack A-form linear + B-form BANK-SWIZZLED (frag g of point (tile,c)
//       at slot ((c>>1)+g)&3 within its 64B row) + ra partial sums + counter=0.
// main: 1024 blocks (16 pairs x 16 strip-groups x 4 target slices); block
//       stages its 64-tile slice (64 KB) into LDS once via global_load_lds,
//       then 4 waves x 4 strips run 64 tiles: ds_read_b128 + 4 MFMA + 16 fmin.
//       Per-q slice-min stored plain to minq[slice][qslot].
// reduce: 64 blocks min over 4 slices + partial sums; last block (counter
//       handshake) adds raPart and writes the scalar. Fixed order everywhere.

typedef __attribute__((ext_vector_type(8))) short short8;
typedef __attribute__((ext_vector_type(4))) float f32x4;

constexpr int NPTS = 4096;
constexpr int NB   = 8;
constexpr int NPOINTS = 2 * NB * NPTS;               // 65536
constexpr size_t PACK_BYTES = (size_t)NPOINTS * 64;  // 4 MB per form
constexpr int SLICES = 4;
constexpr int TPS    = 64;                           // tiles per slice (64*16 pts)
constexpr int MAIN_BLOCKS = 16 * 16 * SLICES;        // pairs x strip-groups x slices
constexpr int RED_BLOCKS  = 64;

__device__ inline unsigned short f2bf(float x) {     // round-to-nearest-even
    unsigned u = __float_as_uint(x);
    unsigned r = u + 0x7fff + ((u >> 16) & 1);
    return (unsigned short)(r >> 16);
}
__device__ inline float bf2f(unsigned short h) {
    return __uint_as_float(((unsigned)h) << 16);
}

__global__ __launch_bounds__(256) void chamfer_prep(
    const float* __restrict__ X, const float* __restrict__ Y,
    unsigned short* __restrict__ Aq, unsigned short* __restrict__ Bt,
    float* __restrict__ raPart, unsigned* __restrict__ counter)
{
    const int P     = blockIdx.x * 256 + threadIdx.x;   // 0..65535
    const int cloud = P >> 15;                          // 0 = X, 1 = Y
    const int b     = (P >> 12) & 7;
    const int p     = P & 4095;

    if (P == 0) *counter = 0;                           // reduce handshake reset

    const float* src = (cloud ? Y : X) + b * 3 * NPTS + p;
    const float v0 = src[0], v1 = src[NPTS], v2 = src[2 * NPTS];
    const float r  = fmaf(v0, v0, fmaf(v1, v1, v2 * v2));

    unsigned qw[8], tw[8];
    qw[7] = 0; tw[7] = 0;
    const float v[3] = {v0, v1, v2};
    #pragma unroll
    for (int c = 0; c < 3; ++c) {
        unsigned short th = f2bf(v[c]);
        unsigned short tl = f2bf(v[c] - bf2f(th));
        float m2 = -2.0f * v[c];
        unsigned short qh = f2bf(m2);
        unsigned short ql = f2bf(m2 - bf2f(qh));
        qw[2 * c]     = (unsigned)qh | ((unsigned)qh << 16);
        qw[2 * c + 1] = (unsigned)ql | ((unsigned)ql << 16);
        tw[2 * c]     = (unsigned)th | ((unsigned)tl << 16);
        tw[2 * c + 1] = (unsigned)th | ((unsigned)tl << 16);
    }
    qw[6] = 0x3F803F80u;                                 // slots 12,13 = 1.0
    unsigned short rh = f2bf(r);
    unsigned short rl = f2bf(r - bf2f(rh));
    tw[6] = (unsigned)rh | ((unsigned)rl << 16);         // slots 12,13 = rt hi/lo

    // A-form: linear, 64 B per point.
    uint4* qa = (uint4*)(Aq + (size_t)P * 32);
    qa[0] = make_uint4(qw[0], qw[1], qw[2], qw[3]);
    qa[1] = make_uint4(qw[4], qw[5], qw[6], qw[7]);
    qa[2] = make_uint4(0, 0, 0, 0);
    qa[3] = make_uint4(0, 0, 0, 0);

    // B-form: swizzled fragment slots within the point's 64B row.
    const int tile = p >> 4, c = p & 15, cr = (c >> 1) & 3;
    char* tb = (char*)Bt + (size_t)(cloud * NB + b) * (NPTS * 64)
             + (size_t)tile * 1024 + c * 64;
    uint4 f0 = make_uint4(tw[0], tw[1], tw[2], tw[3]);   // k 0..7
    uint4 f1 = make_uint4(tw[4], tw[5], tw[6], tw[7]);   // k 8..15
    uint4 fz = make_uint4(0, 0, 0, 0);                   // k 16..31
    *(uint4*)(tb + ((cr + 0) & 3) * 16) = f0;
    *(uint4*)(tb + ((cr + 1) & 3) * 16) = f1;
    *(uint4*)(tb + ((cr + 2) & 3) * 16) = fz;
    *(uint4*)(tb + ((cr + 3) & 3) * 16) = fz;

    // Partial sums of ||p||^2 (every point is a query in exactly one dir).
    __shared__ float wsum[4];
    float acc = r;
    #pragma unroll
    for (int off = 32; off > 0; off >>= 1) acc += __shfl_down(acc, off);
    if ((threadIdx.x & 63) == 0) wsum[threadIdx.x >> 6] = acc;
    __syncthreads();
    if (threadIdx.x == 0)
        raPart[blockIdx.x] = (wsum[0] + wsum[1]) + (wsum[2] + wsum[3]);
}

__global__ __launch_bounds__(256, 2) void chamfer_mfma(
    const unsigned short* __restrict__ Aq, const unsigned short* __restrict__ Bt,
    float* __restrict__ minq)
{
    __shared__ char sB[TPS * 1024];                     // 64 KB target slice

    const int bid   = blockIdx.x;
    const int slice = bid & 3;
    const int sg    = (bid >> 2) & 15;
    const int pair  = bid >> 6;                         // dir*8 + b
    const int dir   = pair >> 3, b = pair & 7;
    const int lane  = threadIdx.x & 63;
    const int wv    = threadIdx.x >> 6;
    const int c     = lane & 15, g = lane >> 4;

    const char* Ab = (const char*)Aq + (size_t)(dir * NB + b) * (NPTS * 64);
    const char* Bb = (const char*)Bt + (size_t)((1 - dir) * NB + b) * (NPTS * 64)
                   + (size_t)slice * (TPS * 1024);

    // Stage slice into LDS: linear dest (wave-uniform base + lane*16),
    // pre-swizzled source layout.
    {
        const char* gsrc = Bb + wv * 16384 + lane * 16;
        char*       lb   = sB + wv * 16384;
        #pragma unroll
        for (int j = 0; j < 16; ++j) {
            __builtin_amdgcn_global_load_lds(
                (const __attribute__((address_space(1))) void*)(gsrc + j * 1024),
                (__attribute__((address_space(3))) void*)(lb + j * 1024),
                16, 0, 0);
        }
    }

    // A fragments: 4 strips of 16 queries per wave (linear layout).
    const int strip0 = sg * 16 + wv * 4;
    const int lsel_a = c * 64 + g * 16;
    short8 A0 = *(const short8*)(Ab + (size_t)(strip0 + 0) * 1024 + lsel_a);
    short8 A1 = *(const short8*)(Ab + (size_t)(strip0 + 1) * 1024 + lsel_a);
    short8 A2 = *(const short8*)(Ab + (size_t)(strip0 + 2) * 1024 + lsel_a);
    short8 A3 = *(const short8*)(Ab + (size_t)(strip0 + 3) * 1024 + lsel_a);

    __syncthreads();                                    // LDS staged

    f32x4 run[4];
    #pragma unroll
    for (int s = 0; s < 4; ++s)
        run[s] = (f32x4){3.4e38f, 3.4e38f, 3.4e38f, 3.4e38f};
    const f32x4 zero = (f32x4){0.f, 0.f, 0.f, 0.f};

    // Swizzled fragment read: lane (c,g) reads slot ((c>>1)+g)&3 of row c.
    const char* sbase = sB + c * 64 + ((((c >> 1) + g) & 3) * 16);

    #pragma unroll 4
    for (int t = 0; t < TPS; ++t) {
        short8 bf = *(const short8*)(sbase + t * 1024);  // ds_read_b128
        f32x4 d0 = __builtin_amdgcn_mfma_f32_16x16x32_bf16(A0, bf, zero, 0, 0, 0);
        f32x4 d1 = __builtin_amdgcn_mfma_f32_16x16x32_bf16(A1, bf, zero, 0, 0, 0);
        f32x4 d2 = __builtin_amdgcn_mfma_f32_16x16x32_bf16(A2, bf, zero, 0, 0, 0);
        f32x4 d3 = __builtin_amdgcn_mfma_f32_16x16x32_bf16(A3, bf, zero, 0, 0, 0);
        #pragma unroll
        for (int i = 0; i < 4; ++i) {
            run[0][i] = fminf(run[0][i], d0[i]);
            run[1][i] = fminf(run[1][i], d1[i]);
            run[2][i] = fminf(run[2][i], d2[i]);
            run[3][i] = fminf(run[3][i], d3[i]);
        }
    }

    // D layout: col (t) = lane&15, row (q) = (lane>>4)*4 + reg.
    // Min over the 16 t-lanes: butterfly over lane bits 0..3.
    #pragma unroll
    for (int st = 1; st < 16; st <<= 1) {
        #pragma unroll
        for (int s = 0; s < 4; ++s) {
            #pragma unroll
            for (int i = 0; i < 4; ++i)
                run[s][i] = fminf(run[s][i], __shfl_xor(run[s][i], st));
        }
    }

    // Lane (g,c) emits q-min for strip s=c>>2, reg i=c&3 (static select).
    float val = run[0][0];
    #pragma unroll
    for (int s = 0; s < 4; ++s)
        #pragma unroll
        for (int i = 0; i < 4; ++i)
            if (c == s * 4 + i) val = run[s][i];

    const int qidx = (strip0 + (c >> 2)) * 16 + g * 4 + (c & 3);
    minq[(size_t)slice * NPOINTS + pair * NPTS + qidx] = val;
}

__global__ __launch_bounds__(256) void chamfer_reduce(
    const float4* __restrict__ mq4, const float* __restrict__ raPart,
    float* __restrict__ partials, unsigned* __restrict__ counter,
    float* __restrict__ out)
{
    __shared__ float w1[4], w2[4];
    __shared__ int lastFlag;
    const int tid = threadIdx.x;
    const int idx = blockIdx.x * 256 + tid;             // 0..16383 float4 slots

    float4 m = mq4[idx];
    #pragma unroll
    for (int s = 1; s < SLICES; ++s) {
        float4 v = mq4[(size_t)s * (NPOINTS / 4) + idx];
        m.x = fminf(m.x, v.x); m.y = fminf(m.y, v.y);
        m.z = fminf(m.z, v.z); m.w = fminf(m.w, v.w);
    }
    float v = (m.x + m.y) + (m.z + m.w);
    #pragma unroll
    for (int off = 32; off > 0; off >>= 1) v += __shfl_down(v, off);
    if ((tid & 63) == 0) w1[tid >> 6] = v;
    __syncthreads();
    if (tid == 0) {
        partials[blockIdx.x] = (w1[0] + w1[1]) + (w1[2] + w1[3]);
        __threadfence();
        unsigned old = atomicAdd(counter, 1u);
        lastFlag = (old == RED_BLOCKS - 1);
    }
    __syncthreads();

    if (lastFlag) {
        __threadfence();                                 // acquire partials
        float acc = raPart[tid];                         // 256 ra partials
        if (tid < RED_BLOCKS) acc += partials[tid];
        #pragma unroll
        for (int off = 32; off > 0; off >>= 1) acc += __shfl_down(acc, off);
        if ((tid & 63) == 0) w2[tid >> 6] = acc;
        __syncthreads();
        if (tid == 0) {
            // mean over [B, N] of (d1+d2)/2 -> total / 65536
            out[0] = ((w2[0] + w2[1]) + (w2[2] + w2[3])) * (1.0f / 65536.0f);
        }
    }
}

extern "C" void kernel_launch(void* const* d_in, const int* in_sizes, int n_in,
                              void* d_out, int out_size, void* d_ws, size_t ws_size,
                              hipStream_t stream) {
    const float* X = (const float*)d_in[0];
    const float* Y = (const float*)d_in[1];

    unsigned short* Aq       = (unsigned short*)d_ws;                      // 4 MB
    unsigned short* Bt       = (unsigned short*)((char*)d_ws + PACK_BYTES);// 4 MB
    float*          minq     = (float*)((char*)d_ws + 2 * PACK_BYTES);     // 1 MB
    float*          raPart   = minq + (size_t)SLICES * NPOINTS;            // 256
    float*          partials = raPart + 256;                               // 64
    unsigned*       counter  = (unsigned*)(partials + RED_BLOCKS);         // 1
    float*          out      = (float*)d_out;

    chamfer_prep<<<256, 256, 0, stream>>>(X, Y, Aq, Bt, raPart, counter);
    chamfer_mfma<<<MAIN_BLOCKS, 256, 0, stream>>>(Aq, Bt, minq);
    chamfer_reduce<<<RED_BLOCKS, 256, 0, stream>>>(
        (const float4*)minq, raPart, partials, counter, out);
}

// Round 8
// 35.598 us; speedup vs baseline: 1.8788x; 1.0305x over previous
//
#include <hip/hip_runtime.h>

// Chamfer loss, single fused kernel. X, Y f32 [8, 3, 4096] -> scalar.
// dir 0: queries = X, targets = Y; dir 1: queries = Y, targets = X.
//
// d'(q,t) = ||t||^2 - 2 q.t via mfma_f32_16x16x32_bf16 with hi/lo-split bf16
// (verified R6/R7, absmax 0). Only k0..13 carry data -> 32 B/target; A-lanes
// g>=2 are zero registers so B k16..31 are don't-care (lanes re-read g0/g1).
// Whole target cloud (4096 pts) packed in 128 KB LDS -> no slices.
//
// 256 blocks (1/CU) x 256 thr: block = (pair, 256-query group).
//   pack B->LDS (XOR-swizzled, b128-optimal banks), A->registers,
//   256 tiles x (ds_read_b128 + 4 MFMA + 16 fmin), butterfly-min,
//   + ra, block sum -> partials[bid]; counter handshake ((old&255)==255,
//   poison-proof) -> firing block sums 256 partials -> out.

typedef __attribute__((ext_vector_type(8))) short short8;
typedef __attribute__((ext_vector_type(4))) float f32x4;
typedef __attribute__((ext_vector_type(4))) unsigned uint4v;

constexpr int NPTS = 4096;
constexpr int NB   = 8;
constexpr int GRID = 256;

union Frag { uint4v u; short8 s; };

__device__ inline unsigned short f2bf(float x) {      // round-to-nearest-even
    unsigned u = __float_as_uint(x);
    unsigned r = u + 0x7fff + ((u >> 16) & 1);
    return (unsigned short)(r >> 16);
}
__device__ inline float bf2f(unsigned short h) {
    return __uint_as_float(((unsigned)h) << 16);
}
__device__ inline unsigned pack2(unsigned short a, unsigned short b) {
    return (unsigned)a | ((unsigned)b << 16);
}

__global__ __launch_bounds__(256, 1) void chamfer_fused(
    const float* __restrict__ X, const float* __restrict__ Y,
    float* __restrict__ partials, unsigned* __restrict__ counter,
    float* __restrict__ out)
{
    __shared__ char  BL[131072];        // 4096 targets x 32 B, swizzled
    __shared__ float wsum[4];
    __shared__ float fsum[4];
    __shared__ int   fireFlag;

    const int bid  = blockIdx.x;
    const int qg   = bid & 15;
    const int pair = bid >> 4;          // dir*8 + b
    const int dir  = pair >> 3, b = pair & 7;
    const int tid  = threadIdx.x;
    const int lane = tid & 63, wv = tid >> 6;
    const int c    = lane & 15, g = lane >> 4;

    const float* __restrict__ Qraw = (dir ? Y : X) + b * 3 * NPTS;
    const float* __restrict__ Traw = (dir ? X : Y) + b * 3 * NPTS;

    // ---- pack target cloud into LDS (32 B per point, k0..15) ----
    for (int k = 0; k < 16; ++k) {
        const int p = k * 256 + tid;                      // coalesced
        float tx = Traw[p], ty = Traw[NPTS + p], tz = Traw[2 * NPTS + p];
        float r  = fmaf(tx, tx, fmaf(ty, ty, tz * tz));
        unsigned short hx = f2bf(tx), lx = f2bf(tx - bf2f(hx));
        unsigned short hy = f2bf(ty), ly = f2bf(ty - bf2f(hy));
        unsigned short hz = f2bf(tz), lz = f2bf(tz - bf2f(hz));
        unsigned short hr = f2bf(r),  lr = f2bf(r  - bf2f(hr));
        unsigned wx = pack2(hx, lx), wy = pack2(hy, ly);
        unsigned wz = pack2(hz, lz), wr = pack2(hr, lr);
        uint4v lo = {wx, wx, wy, wy};                     // k0..7 : coords 0,1
        uint4v hi = {wz, wz, wr, 0u};                     // k8..15: coord 2, r, 0
        const int swz = ((p >> 2) & 7) << 4;
        *(uint4v*)(BL + ((p * 32 +  0) ^ swz)) = lo;
        *(uint4v*)(BL + ((p * 32 + 16) ^ swz)) = hi;
    }

    // ---- A fragments in registers: 4 strips of 16 queries per wave ----
    Frag afr[4];
    const int qbase0 = qg * 256 + (wv * 4) * 16 + c;
    #pragma unroll
    for (int s = 0; s < 4; ++s) {
        const int q = qbase0 + s * 16;
        float qx = Qraw[q], qy = Qraw[NPTS + q], qz = Qraw[2 * NPTS + q];
        float mx = -2.f * qx, my = -2.f * qy, mz = -2.f * qz;
        unsigned short hx = f2bf(mx), lx = f2bf(mx - bf2f(hx));
        unsigned short hy = f2bf(my), ly = f2bf(my - bf2f(hy));
        unsigned short hz = f2bf(mz), lz = f2bf(mz - bf2f(hz));
        uint4v f0 = {pack2(hx, hx), pack2(lx, lx), pack2(hy, hy), pack2(ly, ly)};
        uint4v f1 = {pack2(hz, hz), pack2(lz, lz), 0x3F803F80u, 0u};
        uint4v zz = {0u, 0u, 0u, 0u};
        Frag f; f.u = (g == 0) ? f0 : (g == 1) ? f1 : zz;  // g>=2: A = 0
        afr[s] = f;
    }

    __syncthreads();                                       // B staged

    // ---- main loop: 256 target tiles, 2-deep prefetch ----
    f32x4 run[4];
    #pragma unroll
    for (int s = 0; s < 4; ++s)
        run[s] = (f32x4){3.4e38f, 3.4e38f, 3.4e38f, 3.4e38f};
    const f32x4 zacc = (f32x4){0.f, 0.f, 0.f, 0.f};

    const int bsel = c * 32 + (g & 1) * 16;
    const char* pe = BL +       (bsel ^ ((((c >> 2)    ) & 7) << 4));  // even t
    const char* po = BL + 512 + (bsel ^ ((((c >> 2) + 4) & 7) << 4));  // odd t

    short8 bf0 = *(const short8*)(pe);
    short8 bf1 = *(const short8*)(po);
    #pragma unroll 4
    for (int t = 0; t < 256; t += 2) {
        const int t2 = (t + 2) & 255;                      // wrap: dummy tail
        short8 nf0 = *(const short8*)(pe + t2 * 512);
        {
            f32x4 d0 = __builtin_amdgcn_mfma_f32_16x16x32_bf16(afr[0].s, bf0, zacc, 0, 0, 0);
            f32x4 d1 = __builtin_amdgcn_mfma_f32_16x16x32_bf16(afr[1].s, bf0, zacc, 0, 0, 0);
            f32x4 d2 = __builtin_amdgcn_mfma_f32_16x16x32_bf16(afr[2].s, bf0, zacc, 0, 0, 0);
            f32x4 d3 = __builtin_amdgcn_mfma_f32_16x16x32_bf16(afr[3].s, bf0, zacc, 0, 0, 0);
            #pragma unroll
            for (int i = 0; i < 4; ++i) {
                run[0][i] = fminf(run[0][i], d0[i]);
                run[1][i] = fminf(run[1][i], d1[i]);
                run[2][i] = fminf(run[2][i], d2[i]);
                run[3][i] = fminf(run[3][i], d3[i]);
            }
        }
        short8 nf1 = *(const short8*)(po + t2 * 512);
        {
            f32x4 d0 = __builtin_amdgcn_mfma_f32_16x16x32_bf16(afr[0].s, bf1, zacc, 0, 0, 0);
            f32x4 d1 = __builtin_amdgcn_mfma_f32_16x16x32_bf16(afr[1].s, bf1, zacc, 0, 0, 0);
            f32x4 d2 = __builtin_amdgcn_mfma_f32_16x16x32_bf16(afr[2].s, bf1, zacc, 0, 0, 0);
            f32x4 d3 = __builtin_amdgcn_mfma_f32_16x16x32_bf16(afr[3].s, bf1, zacc, 0, 0, 0);
            #pragma unroll
            for (int i = 0; i < 4; ++i) {
                run[0][i] = fminf(run[0][i], d0[i]);
                run[1][i] = fminf(run[1][i], d1[i]);
                run[2][i] = fminf(run[2][i], d2[i]);
                run[3][i] = fminf(run[3][i], d3[i]);
            }
        }
        bf0 = nf0; bf1 = nf1;
    }

    // ---- butterfly min over the 16 t-lanes (lane bits 0..3) ----
    #pragma unroll
    for (int st = 1; st < 16; st <<= 1) {
        #pragma unroll
        for (int s = 0; s < 4; ++s)
            #pragma unroll
            for (int i = 0; i < 4; ++i)
                run[s][i] = fminf(run[s][i], __shfl_xor(run[s][i], st));
    }

    // Lane (c,g) emits q-min for strip s=c>>2, reg i=c&3 (static select).
    float val = run[0][0];
    #pragma unroll
    for (int s = 0; s < 4; ++s)
        #pragma unroll
        for (int i = 0; i < 4; ++i)
            if (c == s * 4 + i) val = run[s][i];

    // ra for this lane's emit query; per-q result = ra + min d'.
    {
        const int qe = qg * 256 + (wv * 4 + (c >> 2)) * 16 + g * 4 + (c & 3);
        float qx = Qraw[qe], qy = Qraw[NPTS + qe], qz = Qraw[2 * NPTS + qe];
        val += fmaf(qx, qx, fmaf(qy, qy, qz * qz));
    }

    // ---- block sum (fixed-order) + handshake ----
    #pragma unroll
    for (int off = 1; off < 64; off <<= 1) val += __shfl_xor(val, off);
    if (lane == 0) wsum[wv] = val;
    __syncthreads();
    if (tid == 0) {
        partials[bid] = (wsum[0] + wsum[1]) + (wsum[2] + wsum[3]);
        __threadfence();                          // publish partial
        unsigned old = atomicAdd(counter, 1u);    // device-scope
        fireFlag = ((old & 255u) == 255u);        // poison-proof: fires once/call
    }
    __syncthreads();

    if (fireFlag) {
        __threadfence();                          // acquire partials
        float p = partials[tid];                  // exactly GRID == 256
        #pragma unroll
        for (int off = 1; off < 64; off <<= 1) p += __shfl_xor(p, off);
        if (lane == 0) fsum[wv] = p;
        __syncthreads();
        if (tid == 0) {
            // mean over [B, N] of (d1+d2)/2 -> total / (2*8*4096)
            out[0] = ((fsum[0] + fsum[1]) + (fsum[2] + fsum[3])) * (1.0f / 65536.0f);
        }
    }
}

extern "C" void kernel_launch(void* const* d_in, const int* in_sizes, int n_in,
                              void* d_out, int out_size, void* d_ws, size_t ws_size,
                              hipStream_t stream) {
    const float* X = (const float*)d_in[0];
    const float* Y = (const float*)d_in[1];

    float*    partials = (float*)d_ws;                 // 256 f32
    unsigned* counter  = (unsigned*)(partials + GRID); // 1 u32 (any init OK)
    float*    out      = (float*)d_out;

    chamfer_fused<<<GRID, 256, 0, stream>>>(X, Y, partials, counter, out);
}

// Round 9
// 33.568 us; speedup vs baseline: 1.9924x; 1.0605x over previous
//
#include <hip/hip_runtime.h>

// Chamfer loss, single fused kernel. X, Y f32 [8, 3, 4096] -> scalar.
// dir 0: queries = X, targets = Y; dir 1: queries = Y, targets = X.
//
// d'(q,t) = ||t||^2 - 2 q.t via mfma_f32_16x16x32_bf16, hi/lo-split bf16
// (verified R6-R8, absmax 0). k0..13 carry data -> 32 B/target; A-lanes
// g>=2 are zero so B k16..31 are don't-care. Whole target cloud in 128 KB LDS.
//
// R9 change: 512 threads (8 waves = 2 waves/SIMD for TLP; R8 had 1/SIMD).
// Wave owns 2 strips of 16 queries; 256 blocks = 16 pairs x 16 query-groups.
// Scalar-only epilogue: butterfly min over t-lanes, butterfly sums, + sum(ra),
// block partial -> counter handshake ((old&255)==255, poison-proof) -> out.

typedef __attribute__((ext_vector_type(8))) short short8;
typedef __attribute__((ext_vector_type(4))) float f32x4;
typedef __attribute__((ext_vector_type(4))) unsigned uint4v;

constexpr int NPTS = 4096;
constexpr int NB   = 8;
constexpr int GRID = 256;
constexpr int TPB  = 512;

union Frag { uint4v u; short8 s; };

__device__ inline unsigned short f2bf(float x) {      // round-to-nearest-even
    unsigned u = __float_as_uint(x);
    unsigned r = u + 0x7fff + ((u >> 16) & 1);
    return (unsigned short)(r >> 16);
}
__device__ inline float bf2f(unsigned short h) {
    return __uint_as_float(((unsigned)h) << 16);
}
__device__ inline unsigned pack2(unsigned short a, unsigned short b) {
    return (unsigned)a | ((unsigned)b << 16);
}

__global__ __launch_bounds__(TPB, 1) void chamfer_fused(
    const float* __restrict__ X, const float* __restrict__ Y,
    float* __restrict__ partials, unsigned* __restrict__ counter,
    float* __restrict__ out)
{
    __shared__ char  BL[131072];        // 4096 targets x 32 B, swizzled
    __shared__ float wsum[8];
    __shared__ float fsum[8];
    __shared__ int   fireFlag;

    const int bid  = blockIdx.x;
    const int qg   = bid & 15;
    const int pair = bid >> 4;          // dir*8 + b
    const int dir  = pair >> 3, b = pair & 7;
    const int tid  = threadIdx.x;
    const int lane = tid & 63, wv = tid >> 6;
    const int c    = lane & 15, g = lane >> 4;

    const float* __restrict__ Qraw = (dir ? Y : X) + b * 3 * NPTS;
    const float* __restrict__ Traw = (dir ? X : Y) + b * 3 * NPTS;

    // ---- pack target cloud into LDS (32 B per point) ----
    for (int k = 0; k < 8; ++k) {
        const int p = k * TPB + tid;                      // coalesced
        float tx = Traw[p], ty = Traw[NPTS + p], tz = Traw[2 * NPTS + p];
        float r  = fmaf(tx, tx, fmaf(ty, ty, tz * tz));
        unsigned short hx = f2bf(tx), lx = f2bf(tx - bf2f(hx));
        unsigned short hy = f2bf(ty), ly = f2bf(ty - bf2f(hy));
        unsigned short hz = f2bf(tz), lz = f2bf(tz - bf2f(hz));
        unsigned short hr = f2bf(r),  lr = f2bf(r  - bf2f(hr));
        unsigned wx = pack2(hx, lx), wy = pack2(hy, ly);
        unsigned wz = pack2(hz, lz), wr = pack2(hr, lr);
        uint4v lo = {wx, wx, wy, wy};                     // k0..7 : coords 0,1
        uint4v hi = {wz, wz, wr, 0u};                     // k8..15: coord 2, r, 0
        const int swz = ((p >> 2) & 7) << 4;
        *(uint4v*)(BL + ((p * 32 +  0) ^ swz)) = lo;
        *(uint4v*)(BL + ((p * 32 + 16) ^ swz)) = hi;
    }

    // ---- A fragments: 2 strips of 16 queries per wave; ra kept for sum ----
    Frag afr[2];
    float ra[2];
    #pragma unroll
    for (int s = 0; s < 2; ++s) {
        const int q = qg * 256 + (wv * 2 + s) * 16 + c;
        float qx = Qraw[q], qy = Qraw[NPTS + q], qz = Qraw[2 * NPTS + q];
        ra[s] = fmaf(qx, qx, fmaf(qy, qy, qz * qz));
        float mx = -2.f * qx, my = -2.f * qy, mz = -2.f * qz;
        unsigned short hx = f2bf(mx), lx = f2bf(mx - bf2f(hx));
        unsigned short hy = f2bf(my), ly = f2bf(my - bf2f(hy));
        unsigned short hz = f2bf(mz), lz = f2bf(mz - bf2f(hz));
        uint4v f0 = {pack2(hx, hx), pack2(lx, lx), pack2(hy, hy), pack2(ly, ly)};
        uint4v f1 = {pack2(hz, hz), pack2(lz, lz), 0x3F803F80u, 0u};
        uint4v zz = {0u, 0u, 0u, 0u};
        Frag f; f.u = (g == 0) ? f0 : (g == 1) ? f1 : zz;  // g>=2: A = 0
        afr[s] = f;
    }

    __syncthreads();                                       // B staged

    // ---- main loop: 256 target tiles, 2-deep prefetch ----
    f32x4 run[2];
    run[0] = (f32x4){3.4e38f, 3.4e38f, 3.4e38f, 3.4e38f};
    run[1] = run[0];
    const f32x4 zacc = (f32x4){0.f, 0.f, 0.f, 0.f};

    const int bsel = c * 32 + (g & 1) * 16;
    const char* pe = BL +       (bsel ^ ((((c >> 2)    ) & 7) << 4));  // even t
    const char* po = BL + 512 + (bsel ^ ((((c >> 2) + 4) & 7) << 4));  // odd t

    short8 bf0 = *(const short8*)(pe);
    short8 bf1 = *(const short8*)(po);
    #pragma unroll 4
    for (int t = 0; t < 256; t += 2) {
        const int t2 = (t + 2) & 255;                      // wrap: dummy tail
        short8 nf0 = *(const short8*)(pe + t2 * 512);
        f32x4 dA0 = __builtin_amdgcn_mfma_f32_16x16x32_bf16(afr[0].s, bf0, zacc, 0, 0, 0);
        f32x4 dA1 = __builtin_amdgcn_mfma_f32_16x16x32_bf16(afr[1].s, bf0, zacc, 0, 0, 0);
        short8 nf1 = *(const short8*)(po + t2 * 512);
        f32x4 dB0 = __builtin_amdgcn_mfma_f32_16x16x32_bf16(afr[0].s, bf1, zacc, 0, 0, 0);
        f32x4 dB1 = __builtin_amdgcn_mfma_f32_16x16x32_bf16(afr[1].s, bf1, zacc, 0, 0, 0);
        #pragma unroll
        for (int i = 0; i < 4; ++i) {
            run[0][i] = fminf(run[0][i], fminf(dA0[i], dB0[i]));  // v_min3
            run[1][i] = fminf(run[1][i], fminf(dA1[i], dB1[i]));
        }
        bf0 = nf0; bf1 = nf1;
    }

    // ---- epilogue (all scalar): min over 16 t-lanes (lane bits 0..3) ----
    #pragma unroll
    for (int st = 1; st < 16; st <<= 1) {
        #pragma unroll
        for (int s = 0; s < 2; ++s)
            #pragma unroll
            for (int i = 0; i < 4; ++i)
                run[s][i] = fminf(run[s][i], __shfl_xor(run[s][i], st));
    }
    // Per lane: sum its 4 rows (rows g*4+i) of each strip; sum over g via
    // butterfly bits 4,5; add strip ra sums (butterfly bits 0..3).
    float msum = ((run[0][0] + run[0][1]) + (run[0][2] + run[0][3]))
               + ((run[1][0] + run[1][1]) + (run[1][2] + run[1][3]));
    msum += __shfl_xor(msum, 16);
    msum += __shfl_xor(msum, 32);
    float rsum = ra[0] + ra[1];
    #pragma unroll
    for (int st = 1; st < 16; st <<= 1) rsum += __shfl_xor(rsum, st);
    // wave contribution = sum over its 32 queries of (ra + min d')
    if (lane == 0) wsum[wv] = msum + rsum;
    __syncthreads();
    if (tid == 0) {
        float acc = ((wsum[0] + wsum[1]) + (wsum[2] + wsum[3]))
                  + ((wsum[4] + wsum[5]) + (wsum[6] + wsum[7]));
        partials[bid] = acc;
        __threadfence();                          // publish partial
        unsigned old = atomicAdd(counter, 1u);    // device-scope
        fireFlag = ((old & 255u) == 255u);        // poison-proof: fires once/call
    }
    __syncthreads();

    if (fireFlag) {
        __threadfence();                          // acquire partials
        float p = 0.0f;
        if (tid < GRID) p = partials[tid];        // waves 0..3 carry data
        #pragma unroll
        for (int off = 1; off < 64; off <<= 1) p += __shfl_xor(p, off);
        if (lane == 0) fsum[wv] = p;
        __syncthreads();
        if (tid == 0) {
            // mean over [B, N] of (d1+d2)/2 -> total / (2*8*4096)
            out[0] = ((fsum[0] + fsum[1]) + (fsum[2] + fsum[3])) * (1.0f / 65536.0f);
        }
    }
}

extern "C" void kernel_launch(void* const* d_in, const int* in_sizes, int n_in,
                              void* d_out, int out_size, void* d_ws, size_t ws_size,
                              hipStream_t stream) {
    const float* X = (const float*)d_in[0];
    const float* Y = (const float*)d_in[1];

    float*    partials = (float*)d_ws;                 // 256 f32
    unsigned* counter  = (unsigned*)(partials + GRID); // 1 u32 (any init OK)
    float*    out      = (float*)d_out;

    chamfer_fused<<<GRID, TPB, 0, stream>>>(X, Y, partials, counter, out);
}